// Round 8
// baseline (126.631 us; speedup 1.0000x reference)
//
#include <hip/hip_runtime.h>
#include <math.h>

#define D 1024
#define NH 8
#define T 8193

// ---- ws float-offsets (no memset; done-counter re-zeroed by k2 each launch) ----
#define OFF_QCLS  0         // 1024
#define OFF_EP    1024      // 8*2048   E-partials [p][c*1024+j]
#define OFF_W     17408     // 8192     [h*1024+j]
#define OFF_G     25600     // 16384    [c*8192 + h*1024 + j]
#define OFF_CH    41984     // 8
#define OFF_CONST 41992     // 2
#define OFF_DONE  41994     // 1 uint
#define OFF_L     42000     // 256*8    l_b [b*8+h]
#define OFF_PLOG  44048     // 256*16   [b*16 + c*8 + h]
#define OFF_SCT   48144     // 8193*8   pe[s*8+h] = e^{score}

static __device__ __forceinline__ float wred(float v) {
    #pragma unroll
    for (int m = 32; m; m >>= 1) v += __shfl_xor(v, m, 64);
    return v;
}

// DPP wave-64 sum, result broadcast to all lanes via readlane(63). VALU only.
#define DPPADD(v, ctrl) \
    ((v) + __int_as_float(__builtin_amdgcn_update_dpp( \
        0, __float_as_int(v), (ctrl), 0xf, 0xf, true)))

static __device__ __forceinline__ float wave_total(float v) {
    v = DPPADD(v, 0x111);   // row_shr:1
    v = DPPADD(v, 0x112);   // row_shr:2
    v = DPPADD(v, 0x114);   // row_shr:4
    v = DPPADD(v, 0x118);   // row_shr:8
    v = DPPADD(v, 0x142);   // row_bcast:15
    v = DPPADD(v, 0x143);   // row_bcast:31
    return __int_as_float(__builtin_amdgcn_readlane(__float_as_int(v), 63));
}

// ============ K1: qcls (blocks 0..255, 4 rows each) + E-partials (256..287) ==
__global__ __launch_bounds__(1024) void k1(const float* __restrict__ Wq,
                                           const float* __restrict__ bq,
                                           const float* __restrict__ ct,
                                           const float* __restrict__ Wc,
                                           const float* __restrict__ Wo,
                                           float* __restrict__ ws) {
    __shared__ float red[16];
    __shared__ float er[4][2][256];
    const int b = blockIdx.x, t = threadIdx.x;
    const int w = t >> 6, lane = t & 63;
    if (b < 256) {                        // qcls rows 4b..4b+3
        int grp = t >> 8, f4 = t & 255;
        int r = b * 4 + grp;
        const float4* wr = (const float4*)(Wq + (size_t)r * D);
        const float4* cv = (const float4*)ct;
        float4 a = wr[f4], c = cv[f4];
        float v = a.x*c.x + a.y*c.y + a.z*c.z + a.w*c.w;
        v = wred(v);
        if (lane == 0) red[w] = v;
        __syncthreads();
        if (t < 4)
            ws[OFF_QCLS + b*4 + t] = red[4*t]+red[4*t+1]+red[4*t+2]+red[4*t+3] + bq[b*4 + t];
    } else {                              // E-partial p over 128 Wo rows, j-quarter
        int idx = b - 256;                // 0..31
        int p = idx >> 2, jq = idx & 3;
        int layer = t >> 8, jl = t & 255;
        int j = jq * 256 + jl;
        int i0 = p * 128 + layer * 32;
        const float* wo = Wo + (size_t)i0 * D + j;
        float a0 = 0.f, a1 = 0.f;
        #pragma unroll 8
        for (int i = 0; i < 32; ++i) {
            float r = wo[(size_t)i * D];
            a0 += Wc[i0 + i] * r;
            a1 += Wc[D + i0 + i] * r;
        }
        er[layer][0][jl] = a0;
        er[layer][1][jl] = a1;
        __syncthreads();
        if (t < 512) {
            int c = t >> 8, jl2 = t & 255;
            ws[OFF_EP + p*2048 + c*1024 + jq*256 + jl2] =
                er[0][c][jl2] + er[1][c][jl2] + er[2][c][jl2] + er[3][c][jl2];
        }
    }
}

// ============ K2: w (0..63) + G (64..127) + ch (128) + const/done (129) ======
__global__ __launch_bounds__(1024) void k2(const float* __restrict__ Wk,
                                           const float* __restrict__ bk,
                                           const float* __restrict__ Wv,
                                           const float* __restrict__ Wc,
                                           const float* __restrict__ bo,
                                           const float* __restrict__ bv,
                                           const float* __restrict__ bc,
                                           float* __restrict__ ws) {
    __shared__ float qh[128];
    __shared__ float el[2][128];
    __shared__ float lw[8][128];
    __shared__ float lg[8][2][128];
    __shared__ float red[32];
    const int b = blockIdx.x, t = threadIdx.x;
    const int w = t >> 6, lane = t & 63;
    if (b < 64) {                         // w[h, je*128..+128], 8 d-layers of 16
        int h = b >> 3, je = b & 7;
        if (t < 128) qh[t] = ws[OFF_QCLS + h*128 + t];
        __syncthreads();
        int layer = t >> 7, jl = t & 127;
        int j = je * 128 + jl, d0 = layer * 16;
        const float* wk = Wk + (size_t)(h*128 + d0) * D + j;
        float acc = 0.f;
        #pragma unroll 8
        for (int d = 0; d < 16; ++d) acc += qh[d0 + d] * wk[(size_t)d * D];
        lw[layer][jl] = acc;
        __syncthreads();
        if (t < 128) {
            float s = 0.f;
            #pragma unroll
            for (int i = 0; i < 8; ++i) s += lw[i][t];
            ws[OFF_W + h*1024 + je*128 + t] = s;
        }
    } else if (b < 128) {                 // G[c, h, je*128..+128], 8 r-layers of 16
        int hb = b - 64, h = hb >> 3, je = hb & 7;
        if (t < 256) {
            int c = t >> 7, r = t & 127;
            float s = 0.f;
            #pragma unroll
            for (int p = 0; p < 8; ++p) s += ws[OFF_EP + p*2048 + c*1024 + h*128 + r];
            el[c][r] = s;
        }
        __syncthreads();
        int layer = t >> 7, jl = t & 127;
        int j = je * 128 + jl, r0 = layer * 16;
        const float* wv = Wv + (size_t)(h*128 + r0) * D + j;
        float a0 = 0.f, a1 = 0.f;
        #pragma unroll 8
        for (int r = 0; r < 16; ++r) {
            float xv = wv[(size_t)r * D];
            a0 += el[0][r0 + r] * xv;
            a1 += el[1][r0 + r] * xv;
        }
        lg[layer][0][jl] = a0;
        lg[layer][1][jl] = a1;
        __syncthreads();
        if (t < 256) {
            int c = t >> 7, jl2 = t & 127;
            float s = 0.f;
            #pragma unroll
            for (int i = 0; i < 8; ++i) s += lg[i][c][jl2];
            ws[OFF_G + c*8192 + h*1024 + je*128 + jl2] = s;
        }
    } else if (b == 128) {                // ch[h] = qcls_h . bk_h
        int h = t >> 7, d = t & 127;
        float v = ws[OFF_QCLS + h*128 + d] * bk[h*128 + d];
        v = wred(v);
        if (lane == 0) red[w] = v;
        __syncthreads();
        if (t < 8) ws[OFF_CH + t] = red[2*t] + red[2*t+1];
    } else {                              // const_c = Wc.bo + E.bv + bc; zero done
        if (t == 0) *((unsigned int*)(ws + OFF_DONE)) = 0u;   // ws is 0xAA-poisoned each launch
        float e0 = 0.f, e1 = 0.f;
        #pragma unroll
        for (int p = 0; p < 8; ++p) {
            e0 += ws[OFF_EP + p*2048 + t];
            e1 += ws[OFF_EP + p*2048 + 1024 + t];
        }
        float v0 = Wc[t]*bo[t] + e0*bv[t];
        float v1 = Wc[D + t]*bo[t] + e1*bv[t];
        v0 = wred(v0); v1 = wred(v1);
        if (lane == 0) { red[w] = v0; red[16 + w] = v1; }
        __syncthreads();
        if (t == 0) {
            float a0 = 0.f, a1 = 0.f;
            #pragma unroll
            for (int i = 0; i < 16; ++i) { a0 += red[i]; a1 += red[16 + i]; }
            ws[OFF_CONST + 0] = a0 + bc[0];
            ws[OFF_CONST + 1] = a1 + bc[1];
        }
    }
}

// ============ K3: x pass + fused finalize (grid 256 x 512) ===================
__global__ __launch_bounds__(512, 2) void k3(const float* __restrict__ x,
                                             const float* __restrict__ ct,
                                             float* __restrict__ out,
                                             float* __restrict__ ws) {
    __shared__ float stash[33 * D];       // 132 KB token rows
    __shared__ float pe[33][8];
    __shared__ float plred[8][8];
    __shared__ unsigned lastFlag;
    __shared__ float lp[32][8];
    __shared__ float rlhs[8];
    __shared__ float r2a[8], r2b[8];
    const int b = blockIdx.x, t = threadIdx.x;
    const int w = t >> 6, lane = t & 63;

    // w fragments in VGPRs: lane l holds float4s {l, l+64, l+128, l+192}
    float4 wreg[8][4];
    const float4* wg4 = (const float4*)(ws + OFF_W);
    #pragma unroll
    for (int h = 0; h < 8; ++h)
        #pragma unroll
        for (int j = 0; j < 4; ++j)
            wreg[h][j] = wg4[h * 256 + j * 64 + lane];
    float chv[8];
    #pragma unroll
    for (int h = 0; h < 8; ++h) chv[h] = ws[OFF_CH + h];

    // async stash fill: wave w owns tokens w*4..w*4+3 (+k=32 for b=255,w=7)
    const int ntok_blk = (b == 255) ? 33 : 32;
    const bool tail = (b == 255 && w == 7);
    const int ntok_w = tail ? 5 : 4;
    for (int i = 0; i < ntok_w; ++i) {
        int k = (i < 4) ? (w * 4 + i) : 32;
        int s = b * 32 + k;
        const float* row = (s == 0) ? ct : (x + (size_t)(s - 1) * D);
        float* dst = stash + k * D;
        #pragma unroll
        for (int q = 0; q < 4; ++q)
            __builtin_amdgcn_global_load_lds(
                (const __attribute__((address_space(1))) unsigned int*)(row + q * 256 + lane * 4),
                (__attribute__((address_space(3))) unsigned int*)(dst + q * 256),
                16, 0, 0);
    }

    const float scale = 0.08838834764831845f;   // 1/sqrt(128)
    auto compute = [&](int k) {
        int s = b * 32 + k;
        const float4* tk = (const float4*)(stash + k * D);
        float4 t0 = tk[lane], t1 = tk[64 + lane], t2 = tk[128 + lane], t3 = tk[192 + lane];
        float pv[8];
        #pragma unroll
        for (int h = 0; h < 8; ++h) {
            float4 w0 = wreg[h][0], w1 = wreg[h][1], w2 = wreg[h][2], w3 = wreg[h][3];
            float v = w0.x*t0.x + w0.y*t0.y + w0.z*t0.z + w0.w*t0.w
                    + w1.x*t1.x + w1.y*t1.y + w1.z*t1.z + w1.w*t1.w
                    + w2.x*t2.x + w2.y*t2.y + w2.z*t2.z + w2.w*t2.w
                    + w3.x*t3.x + w3.y*t3.y + w3.z*t3.z + w3.w*t3.w;
            v = wave_total(v);
            pv[h] = __expf(scale * (v + chv[h]));
        }
        if (lane == 0) {
            float4* sct = (float4*)(ws + OFF_SCT);
            sct[s * 2]     = make_float4(pv[0], pv[1], pv[2], pv[3]);
            sct[s * 2 + 1] = make_float4(pv[4], pv[5], pv[6], pv[7]);
            *(float4*)&pe[k][0] = make_float4(pv[0], pv[1], pv[2], pv[3]);
            *(float4*)&pe[k][4] = make_float4(pv[4], pv[5], pv[6], pv[7]);
        }
    };

    if (!tail) {                          // overlap fetch & compute per token
        __builtin_amdgcn_s_waitcnt(0x0f7c); compute(w*4 + 0);   // vmcnt(12)
        __builtin_amdgcn_s_waitcnt(0x0f78); compute(w*4 + 1);   // vmcnt(8)
        __builtin_amdgcn_s_waitcnt(0x0f74); compute(w*4 + 2);   // vmcnt(4)
        __builtin_amdgcn_s_waitcnt(0x0f70); compute(w*4 + 3);   // vmcnt(0)
    } else {
        __builtin_amdgcn_s_waitcnt(0x0f70);
        for (int i = 0; i < 5; ++i) compute((i < 4) ? (w*4 + i) : 32);
    }
    __syncthreads();

    // l_b[h]
    if (t < 8) {
        float s = 0.f;
        for (int k = 0; k < ntok_blk; ++k) s += pe[k][t];
        ws[OFF_L + b * 8 + t] = s;
    }

    // u_b in registers: thread (half, f4) owns heads 4*half.., float4 j-slice f4
    const int f4 = t & 255, half = t >> 8;
    const float4* st4 = (const float4*)stash;
    float4 acc0 = {0,0,0,0}, acc1 = {0,0,0,0}, acc2 = {0,0,0,0}, acc3 = {0,0,0,0};
    for (int k = 0; k < ntok_blk; ++k) {
        float4 tv = st4[k * 256 + f4];
        float4 pv = *(const float4*)&pe[k][half * 4];
        acc0.x += pv.x*tv.x; acc0.y += pv.x*tv.y; acc0.z += pv.x*tv.z; acc0.w += pv.x*tv.w;
        acc1.x += pv.y*tv.x; acc1.y += pv.y*tv.y; acc1.z += pv.y*tv.z; acc1.w += pv.y*tv.w;
        acc2.x += pv.z*tv.x; acc2.y += pv.z*tv.y; acc2.z += pv.z*tv.z; acc2.w += pv.z*tv.w;
        acc3.x += pv.w*tv.x; acc3.y += pv.w*tv.y; acc3.z += pv.w*tv.z; acc3.w += pv.w*tv.w;
    }

    // plog_b[c][h] = G[c,h,:] . u_b[h,:]   (G is L2-hot, 64 KB total)
    const float4* G4 = (const float4*)(ws + OFF_G);
    float pl[8];
    #pragma unroll
    for (int c = 0; c < 2; ++c) {
        float4 g0 = G4[c*2048 + (half*4 + 0)*256 + f4];
        float4 g1 = G4[c*2048 + (half*4 + 1)*256 + f4];
        float4 g2 = G4[c*2048 + (half*4 + 2)*256 + f4];
        float4 g3 = G4[c*2048 + (half*4 + 3)*256 + f4];
        pl[c*4+0] = g0.x*acc0.x + g0.y*acc0.y + g0.z*acc0.z + g0.w*acc0.w;
        pl[c*4+1] = g1.x*acc1.x + g1.y*acc1.y + g1.z*acc1.z + g1.w*acc1.w;
        pl[c*4+2] = g2.x*acc2.x + g2.y*acc2.y + g2.z*acc2.z + g2.w*acc2.w;
        pl[c*4+3] = g3.x*acc3.x + g3.y*acc3.y + g3.z*acc3.z + g3.w*acc3.w;
    }
    #pragma unroll
    for (int v = 0; v < 8; ++v) pl[v] = wave_total(pl[v]);
    if (lane == 0)
        #pragma unroll
        for (int v = 0; v < 8; ++v) plred[w][v] = pl[v];
    __syncthreads();
    if (t < 16) {                         // combine 4 waves per half
        int c = t >> 3, hh = t & 7;
        int wb = (hh < 4) ? 0 : 4, vi = c * 4 + (hh & 3);
        ws[OFF_PLOG + b*16 + t] =
            plred[wb][vi] + plred[wb+1][vi] + plred[wb+2][vi] + plred[wb+3][vi];
    }

    // ---- done handshake: last block to arrive runs the finalize (old k4) ----
    __syncthreads();                      // all this block's stores drained (vmcnt 0)
    if (t == 0) {
        __threadfence();                  // release: flush XCD L2 to coherent point
        unsigned old = atomicAdd((unsigned*)(ws + OFF_DONE), 1u);
        lastFlag = (old == 255) ? 1u : 0u;
    }
    __syncthreads();
    if (!lastFlag) return;
    if (t == 0) __threadfence();          // acquire: invalidate stale L2 lines
    __syncthreads();

    // 1/l_h from 256 block-partials
    if (t < 256) {
        int seg = t >> 3, h = t & 7;
        float s = 0.f;
        for (int pb = seg; pb < 256; pb += 32) s += ws[OFF_L + pb*8 + h];
        lp[seg][h] = s;
    }
    __syncthreads();
    if (t < 8) {
        float s = 0.f;
        #pragma unroll
        for (int i = 0; i < 32; ++i) s += lp[i][t];
        rlhs[t] = 1.f / s;
    }
    __syncthreads();
    float rl[8];
    #pragma unroll
    for (int h = 0; h < 8; ++h) rl[h] = rlhs[h];

    // A[s], s = 1..8192
    const float4* sct4 = (const float4*)(ws + OFF_SCT);
    for (int i = t; i < 8192; i += 512) {
        int s_ = i + 1;
        float4 pa = sct4[s_ * 2], pb4 = sct4[s_ * 2 + 1];
        float sum = pa.x*rl[0] + pa.y*rl[1] + pa.z*rl[2] + pa.w*rl[3]
                  + pb4.x*rl[4] + pb4.y*rl[5] + pb4.z*rl[6] + pb4.w*rl[7];
        out[7 + i] = sum * 0.125f;
    }

    // logits + scalar outputs
    {
        float v0 = 0.f, v1 = 0.f;
        for (int idx = t; idx < 4096; idx += 512) {
            float val = ws[OFF_PLOG + idx];
            int rem = idx & 15;
            float z = val * rl[rem & 7];
            if ((rem >> 3) == 0) v0 += z; else v1 += z;
        }
        v0 = wred(v0); v1 = wred(v1);
        if (lane == 0) { r2a[w] = v0; r2b[w] = v1; }
        __syncthreads();
        if (t == 0) {
            float a0 = 0.f, a1 = 0.f;
            #pragma unroll
            for (int i = 0; i < 8; ++i) { a0 += r2a[i]; a1 += r2b[i]; }
            float l0 = a0 + ws[OFF_CONST + 0];
            float l1 = a1 + ws[OFF_CONST + 1];
            float mx = fmaxf(l0, l1);
            float e0 = __expf(l0 - mx), e1 = __expf(l1 - mx);
            float inv = 1.f / (e0 + e1);
            float p0 = e0 * inv, p1 = e1 * inv;
            int am = (p1 > p0) ? 1 : 0;
            out[0] = l0; out[1] = l1;
            out[2] = p0; out[3] = p1;
            out[4] = (float)am;
            out[5] = p0; out[6] = p1;
        }
    }
}

extern "C" void kernel_launch(void* const* d_in, const int* in_sizes, int n_in,
                              void* d_out, int out_size, void* d_ws, size_t ws_size,
                              hipStream_t stream) {
    const float* x  = (const float*)d_in[0];
    const float* ct = (const float*)d_in[1];
    const float* Wq = (const float*)d_in[2];
    const float* bq = (const float*)d_in[3];
    const float* Wk = (const float*)d_in[4];
    const float* bk = (const float*)d_in[5];
    const float* Wv = (const float*)d_in[6];
    const float* bv = (const float*)d_in[7];
    const float* Wo = (const float*)d_in[8];
    const float* bo = (const float*)d_in[9];
    const float* Wc = (const float*)d_in[10];
    const float* bc = (const float*)d_in[11];
    float* out = (float*)d_out;
    float* ws  = (float*)d_ws;

    k1<<<dim3(288), dim3(1024), 0, stream>>>(Wq, bq, ct, Wc, Wo, ws);
    k2<<<dim3(130), dim3(1024), 0, stream>>>(Wk, bk, Wv, Wc, bo, bv, bc, ws);
    k3<<<dim3(256), dim3(512),  0, stream>>>(x, ct, out, ws);
}

// Round 9
// 125.908 us; speedup vs baseline: 1.0057x; 1.0057x over previous
//
#include <hip/hip_runtime.h>
#include <math.h>

#define D 1024
#define NH 8
#define T 8193

// ---- ws float-offsets (no memset, no atomics anywhere) ----
#define OFF_QCLS  0         // 1024
#define OFF_EP    1024      // 8*2048   E-partials [p][c*1024+j]
#define OFF_W     17408     // 8192     [h*1024+j]
#define OFF_G     25600     // 16384    [c*8192 + h*1024 + j]
#define OFF_CH    41984     // 8
#define OFF_CONST 41992     // 2
#define OFF_L     42000     // 256*8    l_b [b*8+h]
#define OFF_PLOG  44048     // 256*16   [b*16 + c*8 + h]
#define OFF_SCT   48144     // 8193*8   pe[s*8+h] = e^{score}

static __device__ __forceinline__ float wred(float v) {
    #pragma unroll
    for (int m = 32; m; m >>= 1) v += __shfl_xor(v, m, 64);
    return v;
}

// DPP wave-64 sum, result broadcast to all lanes via readlane(63). VALU only.
#define DPPADD(v, ctrl) \
    ((v) + __int_as_float(__builtin_amdgcn_update_dpp( \
        0, __float_as_int(v), (ctrl), 0xf, 0xf, true)))

static __device__ __forceinline__ float wave_total(float v) {
    v = DPPADD(v, 0x111);   // row_shr:1
    v = DPPADD(v, 0x112);   // row_shr:2
    v = DPPADD(v, 0x114);   // row_shr:4
    v = DPPADD(v, 0x118);   // row_shr:8
    v = DPPADD(v, 0x142);   // row_bcast:15
    v = DPPADD(v, 0x143);   // row_bcast:31
    return __int_as_float(__builtin_amdgcn_readlane(__float_as_int(v), 63));
}

// ============ K1: qcls (blocks 0..255, 4 rows each) + E-partials (256..287) ==
__global__ __launch_bounds__(1024) void k1(const float* __restrict__ Wq,
                                           const float* __restrict__ bq,
                                           const float* __restrict__ ct,
                                           const float* __restrict__ Wc,
                                           const float* __restrict__ Wo,
                                           float* __restrict__ ws) {
    __shared__ float red[16];
    __shared__ float er[4][2][256];
    const int b = blockIdx.x, t = threadIdx.x;
    const int w = t >> 6, lane = t & 63;
    if (b < 256) {                        // qcls rows 4b..4b+3
        int grp = t >> 8, f4 = t & 255;
        int r = b * 4 + grp;
        const float4* wr = (const float4*)(Wq + (size_t)r * D);
        const float4* cv = (const float4*)ct;
        float4 a = wr[f4], c = cv[f4];
        float v = a.x*c.x + a.y*c.y + a.z*c.z + a.w*c.w;
        v = wred(v);
        if (lane == 0) red[w] = v;
        __syncthreads();
        if (t < 4)
            ws[OFF_QCLS + b*4 + t] = red[4*t]+red[4*t+1]+red[4*t+2]+red[4*t+3] + bq[b*4 + t];
    } else {                              // E-partial p over 128 Wo rows, j-quarter
        int idx = b - 256;                // 0..31
        int p = idx >> 2, jq = idx & 3;
        int layer = t >> 8, jl = t & 255;
        int j = jq * 256 + jl;
        int i0 = p * 128 + layer * 32;
        const float* wo = Wo + (size_t)i0 * D + j;
        float a0 = 0.f, a1 = 0.f;
        #pragma unroll 8
        for (int i = 0; i < 32; ++i) {
            float r = wo[(size_t)i * D];
            a0 += Wc[i0 + i] * r;
            a1 += Wc[D + i0 + i] * r;
        }
        er[layer][0][jl] = a0;
        er[layer][1][jl] = a1;
        __syncthreads();
        if (t < 512) {
            int c = t >> 8, jl2 = t & 255;
            ws[OFF_EP + p*2048 + c*1024 + jq*256 + jl2] =
                er[0][c][jl2] + er[1][c][jl2] + er[2][c][jl2] + er[3][c][jl2];
        }
    }
}

// ============ K2: w (0..63) + G (64..127) + ch (128) + const (129) ===========
__global__ __launch_bounds__(1024) void k2(const float* __restrict__ Wk,
                                           const float* __restrict__ bk,
                                           const float* __restrict__ Wv,
                                           const float* __restrict__ Wc,
                                           const float* __restrict__ bo,
                                           const float* __restrict__ bv,
                                           const float* __restrict__ bc,
                                           float* __restrict__ ws) {
    __shared__ float qh[128];
    __shared__ float el[2][128];
    __shared__ float lw[8][128];
    __shared__ float lg[8][2][128];
    __shared__ float red[32];
    const int b = blockIdx.x, t = threadIdx.x;
    const int w = t >> 6, lane = t & 63;
    if (b < 64) {                         // w[h, je*128..+128], 8 d-layers of 16
        int h = b >> 3, je = b & 7;
        if (t < 128) qh[t] = ws[OFF_QCLS + h*128 + t];
        __syncthreads();
        int layer = t >> 7, jl = t & 127;
        int j = je * 128 + jl, d0 = layer * 16;
        const float* wk = Wk + (size_t)(h*128 + d0) * D + j;
        float acc = 0.f;
        #pragma unroll 8
        for (int d = 0; d < 16; ++d) acc += qh[d0 + d] * wk[(size_t)d * D];
        lw[layer][jl] = acc;
        __syncthreads();
        if (t < 128) {
            float s = 0.f;
            #pragma unroll
            for (int i = 0; i < 8; ++i) s += lw[i][t];
            ws[OFF_W + h*1024 + je*128 + t] = s;
        }
    } else if (b < 128) {                 // G[c, h, je*128..+128], 8 r-layers of 16
        int hb = b - 64, h = hb >> 3, je = hb & 7;
        if (t < 256) {
            int c = t >> 7, r = t & 127;
            float s = 0.f;
            #pragma unroll
            for (int p = 0; p < 8; ++p) s += ws[OFF_EP + p*2048 + c*1024 + h*128 + r];
            el[c][r] = s;
        }
        __syncthreads();
        int layer = t >> 7, jl = t & 127;
        int j = je * 128 + jl, r0 = layer * 16;
        const float* wv = Wv + (size_t)(h*128 + r0) * D + j;
        float a0 = 0.f, a1 = 0.f;
        #pragma unroll 8
        for (int r = 0; r < 16; ++r) {
            float xv = wv[(size_t)r * D];
            a0 += el[0][r0 + r] * xv;
            a1 += el[1][r0 + r] * xv;
        }
        lg[layer][0][jl] = a0;
        lg[layer][1][jl] = a1;
        __syncthreads();
        if (t < 256) {
            int c = t >> 7, jl2 = t & 127;
            float s = 0.f;
            #pragma unroll
            for (int i = 0; i < 8; ++i) s += lg[i][c][jl2];
            ws[OFF_G + c*8192 + h*1024 + je*128 + jl2] = s;
        }
    } else if (b == 128) {                // ch[h] = qcls_h . bk_h
        int h = t >> 7, d = t & 127;
        float v = ws[OFF_QCLS + h*128 + d] * bk[h*128 + d];
        v = wred(v);
        if (lane == 0) red[w] = v;
        __syncthreads();
        if (t < 8) ws[OFF_CH + t] = red[2*t] + red[2*t+1];
    } else {                              // const_c = Wc.bo + E.bv + bc
        float e0 = 0.f, e1 = 0.f;
        #pragma unroll
        for (int p = 0; p < 8; ++p) {
            e0 += ws[OFF_EP + p*2048 + t];
            e1 += ws[OFF_EP + p*2048 + 1024 + t];
        }
        float v0 = Wc[t]*bo[t] + e0*bv[t];
        float v1 = Wc[D + t]*bo[t] + e1*bv[t];
        v0 = wred(v0); v1 = wred(v1);
        if (lane == 0) { red[w] = v0; red[16 + w] = v1; }
        __syncthreads();
        if (t == 0) {
            float a0 = 0.f, a1 = 0.f;
            #pragma unroll
            for (int i = 0; i < 16; ++i) { a0 += red[i]; a1 += red[16 + i]; }
            ws[OFF_CONST + 0] = a0 + bc[0];
            ws[OFF_CONST + 1] = a1 + bc[1];
        }
    }
}

// ============ K3: x single pass: pe + l_b + plog_b  (grid 256 x 512) =========
// G fragment prefetched into registers BEFORE the stash fills so its L2 reads
// hide under the HBM fetch instead of serializing in the stage-C tail.
__global__ __launch_bounds__(512, 2) void k3(const float* __restrict__ x,
                                             const float* __restrict__ ct,
                                             float* __restrict__ ws) {
    __shared__ float stash[33 * D];       // 132 KB token rows
    __shared__ float pe[33][8];
    __shared__ float plred[8][8];
    const int b = blockIdx.x, t = threadIdx.x;
    const int w = t >> 6, lane = t & 63;

    // w fragments in VGPRs: lane l holds float4s {l, l+64, l+128, l+192}
    float4 wreg[8][4];
    const float4* wg4 = (const float4*)(ws + OFF_W);
    #pragma unroll
    for (int h = 0; h < 8; ++h)
        #pragma unroll
        for (int j = 0; j < 4; ++j)
            wreg[h][j] = wg4[h * 256 + j * 64 + lane];
    float chv[8];
    #pragma unroll
    for (int h = 0; h < 8; ++h) chv[h] = ws[OFF_CH + h];

    // G fragment for this thread's stage-C slice (2 classes x 4 heads x float4)
    const int f4 = t & 255, half = t >> 8;
    const float4* G4 = (const float4*)(ws + OFF_G);
    float4 greg[2][4];
    #pragma unroll
    for (int c = 0; c < 2; ++c)
        #pragma unroll
        for (int e = 0; e < 4; ++e)
            greg[c][e] = G4[c*2048 + (half*4 + e)*256 + f4];

    // async stash fill: wave w owns tokens w*4..w*4+3 (+k=32 for b=255,w=7)
    const int ntok_blk = (b == 255) ? 33 : 32;
    const bool tail = (b == 255 && w == 7);
    const int ntok_w = tail ? 5 : 4;
    for (int i = 0; i < ntok_w; ++i) {
        int k = (i < 4) ? (w * 4 + i) : 32;
        int s = b * 32 + k;
        const float* row = (s == 0) ? ct : (x + (size_t)(s - 1) * D);
        float* dst = stash + k * D;
        #pragma unroll
        for (int q = 0; q < 4; ++q)
            __builtin_amdgcn_global_load_lds(
                (const __attribute__((address_space(1))) unsigned int*)(row + q * 256 + lane * 4),
                (__attribute__((address_space(3))) unsigned int*)(dst + q * 256),
                16, 0, 0);
    }

    const float scale = 0.08838834764831845f;   // 1/sqrt(128)
    auto compute = [&](int k) {
        int s = b * 32 + k;
        const float4* tk = (const float4*)(stash + k * D);
        float4 t0 = tk[lane], t1 = tk[64 + lane], t2 = tk[128 + lane], t3 = tk[192 + lane];
        float pv[8];
        #pragma unroll
        for (int h = 0; h < 8; ++h) {
            float4 w0 = wreg[h][0], w1 = wreg[h][1], w2 = wreg[h][2], w3 = wreg[h][3];
            float v = w0.x*t0.x + w0.y*t0.y + w0.z*t0.z + w0.w*t0.w
                    + w1.x*t1.x + w1.y*t1.y + w1.z*t1.z + w1.w*t1.w
                    + w2.x*t2.x + w2.y*t2.y + w2.z*t2.z + w2.w*t2.w
                    + w3.x*t3.x + w3.y*t3.y + w3.z*t3.z + w3.w*t3.w;
            v = wave_total(v);
            pv[h] = __expf(scale * (v + chv[h]));
        }
        if (lane == 0) {
            float4* sct = (float4*)(ws + OFF_SCT);
            sct[s * 2]     = make_float4(pv[0], pv[1], pv[2], pv[3]);
            sct[s * 2 + 1] = make_float4(pv[4], pv[5], pv[6], pv[7]);
            *(float4*)&pe[k][0] = make_float4(pv[0], pv[1], pv[2], pv[3]);
            *(float4*)&pe[k][4] = make_float4(pv[4], pv[5], pv[6], pv[7]);
        }
    };

    if (!tail) {                          // overlap fetch & compute per token
        __builtin_amdgcn_s_waitcnt(0x0f7c); compute(w*4 + 0);   // vmcnt(12)
        __builtin_amdgcn_s_waitcnt(0x0f78); compute(w*4 + 1);   // vmcnt(8)
        __builtin_amdgcn_s_waitcnt(0x0f74); compute(w*4 + 2);   // vmcnt(4)
        __builtin_amdgcn_s_waitcnt(0x0f70); compute(w*4 + 3);   // vmcnt(0)
    } else {
        __builtin_amdgcn_s_waitcnt(0x0f70);
        for (int i = 0; i < 5; ++i) compute((i < 4) ? (w*4 + i) : 32);
    }
    __syncthreads();

    // l_b[h]
    if (t < 8) {
        float s = 0.f;
        for (int k = 0; k < ntok_blk; ++k) s += pe[k][t];
        ws[OFF_L + b * 8 + t] = s;
    }

    // u_b in registers: thread (half, f4) owns heads 4*half.., float4 j-slice f4
    const float4* st4 = (const float4*)stash;
    float4 acc0 = {0,0,0,0}, acc1 = {0,0,0,0}, acc2 = {0,0,0,0}, acc3 = {0,0,0,0};
    for (int k = 0; k < ntok_blk; ++k) {
        float4 tv = st4[k * 256 + f4];
        float4 pv = *(const float4*)&pe[k][half * 4];
        acc0.x += pv.x*tv.x; acc0.y += pv.x*tv.y; acc0.z += pv.x*tv.z; acc0.w += pv.x*tv.w;
        acc1.x += pv.y*tv.x; acc1.y += pv.y*tv.y; acc1.z += pv.y*tv.z; acc1.w += pv.y*tv.w;
        acc2.x += pv.z*tv.x; acc2.y += pv.z*tv.y; acc2.z += pv.z*tv.z; acc2.w += pv.z*tv.w;
        acc3.x += pv.w*tv.x; acc3.y += pv.w*tv.y; acc3.z += pv.w*tv.z; acc3.w += pv.w*tv.w;
    }

    // plog_b[c][h] = G[c,h,:] . u_b[h,:]   (G already in registers)
    float pl[8];
    #pragma unroll
    for (int c = 0; c < 2; ++c) {
        float4 g0 = greg[c][0], g1 = greg[c][1], g2 = greg[c][2], g3 = greg[c][3];
        pl[c*4+0] = g0.x*acc0.x + g0.y*acc0.y + g0.z*acc0.z + g0.w*acc0.w;
        pl[c*4+1] = g1.x*acc1.x + g1.y*acc1.y + g1.z*acc1.z + g1.w*acc1.w;
        pl[c*4+2] = g2.x*acc2.x + g2.y*acc2.y + g2.z*acc2.z + g2.w*acc2.w;
        pl[c*4+3] = g3.x*acc3.x + g3.y*acc3.y + g3.z*acc3.z + g3.w*acc3.w;
    }
    #pragma unroll
    for (int v = 0; v < 8; ++v) pl[v] = wave_total(pl[v]);
    if (lane == 0)
        #pragma unroll
        for (int v = 0; v < 8; ++v) plred[w][v] = pl[v];
    __syncthreads();
    if (t < 16) {                         // combine 4 waves per half
        int c = t >> 3, hh = t & 7;
        int wb = (hh < 4) ? 0 : 4, vi = c * 4 + (hh & 3);
        ws[OFF_PLOG + b*16 + t] =
            plred[wb][vi] + plred[wb+1][vi] + plred[wb+2][vi] + plred[wb+3][vi];
    }
}

// ============ K4: rlh + A + logits (block 0)  (grid 256 x 256) ===============
__global__ __launch_bounds__(256) void k4(float* __restrict__ out,
                                          float* __restrict__ ws) {
    __shared__ float lp[32][8];
    __shared__ float rlh[8];
    __shared__ float r2[8];
    const int b = blockIdx.x, t = threadIdx.x;

    {   // global 1/l_h (redundant per block)
        int seg = t >> 3, h = t & 7;
        float s = 0.f;
        for (int pb = seg; pb < 256; pb += 32) s += ws[OFF_L + pb*8 + h];
        lp[seg][h] = s;
    }
    __syncthreads();
    if (t < 8) {
        float s = 0.f;
        #pragma unroll
        for (int i = 0; i < 32; ++i) s += lp[i][t];
        rlh[t] = 1.f / s;
    }
    __syncthreads();

    // A[s], s = b*32 + t + 1  (pe already stored in SCT)
    if (t < 32) {
        int s_ = b * 32 + t + 1;
        const float4* sct = (const float4*)(ws + OFF_SCT);
        float4 pa = sct[s_ * 2], pb4 = sct[s_ * 2 + 1];
        float sum = pa.x*rlh[0] + pa.y*rlh[1] + pa.z*rlh[2] + pa.w*rlh[3]
                  + pb4.x*rlh[4] + pb4.y*rlh[5] + pb4.z*rlh[6] + pb4.w*rlh[7];
        out[6 + s_] = sum * 0.125f;
    }

    if (b == 0) {                         // logits + scalar outputs
        float v0 = 0.f, v1 = 0.f;
        for (int idx = t; idx < 4096; idx += 256) {
            float val = ws[OFF_PLOG + idx];
            int rem = idx & 15;
            float z = val * rlh[rem & 7];
            if ((rem >> 3) == 0) v0 += z; else v1 += z;
        }
        v0 = wred(v0); v1 = wred(v1);
        if ((t & 63) == 0) { r2[t >> 6] = v0; r2[4 + (t >> 6)] = v1; }
        __syncthreads();
        if (t == 0) {
            float l0 = r2[0]+r2[1]+r2[2]+r2[3] + ws[OFF_CONST + 0];
            float l1 = r2[4]+r2[5]+r2[6]+r2[7] + ws[OFF_CONST + 1];
            float mx = fmaxf(l0, l1);
            float e0 = __expf(l0 - mx), e1 = __expf(l1 - mx);
            float inv = 1.f / (e0 + e1);
            float p0 = e0 * inv, p1 = e1 * inv;
            int am = (p1 > p0) ? 1 : 0;
            out[0] = l0; out[1] = l1;
            out[2] = p0; out[3] = p1;
            out[4] = (float)am;
            out[5] = p0; out[6] = p1;
        }
    }
}

extern "C" void kernel_launch(void* const* d_in, const int* in_sizes, int n_in,
                              void* d_out, int out_size, void* d_ws, size_t ws_size,
                              hipStream_t stream) {
    const float* x  = (const float*)d_in[0];
    const float* ct = (const float*)d_in[1];
    const float* Wq = (const float*)d_in[2];
    const float* bq = (const float*)d_in[3];
    const float* Wk = (const float*)d_in[4];
    const float* bk = (const float*)d_in[5];
    const float* Wv = (const float*)d_in[6];
    const float* bv = (const float*)d_in[7];
    const float* Wo = (const float*)d_in[8];
    const float* bo = (const float*)d_in[9];
    const float* Wc = (const float*)d_in[10];
    const float* bc = (const float*)d_in[11];
    float* out = (float*)d_out;
    float* ws  = (float*)d_ws;

    k1<<<dim3(288), dim3(1024), 0, stream>>>(Wq, bq, ct, Wc, Wo, ws);
    k2<<<dim3(130), dim3(1024), 0, stream>>>(Wk, bk, Wv, Wc, bo, bv, bc, ws);
    k3<<<dim3(256), dim3(512),  0, stream>>>(x, ct, ws);
    k4<<<dim3(256), dim3(256),  0, stream>>>(out, ws);
}

// Round 10
// 123.242 us; speedup vs baseline: 1.0275x; 1.0216x over previous
//
#include <hip/hip_runtime.h>
#include <math.h>

#define D 1024
#define NH 8
#define T 8193

// ---- ws float-offsets (no memset, no atomics anywhere) ----
#define OFF_QCLS  0         // 1024
#define OFF_EP    1024      // 8*2048   E-partials [p][c*1024+j]
#define OFF_W     17408     // 8192     [h*1024+j]
#define OFF_G     25600     // 16384    [c*8192 + h*1024 + j]
#define OFF_CH    41984     // 8
#define OFF_CONST 41992     // 2
#define OFF_L     42000     // 256*8    l_b [b*8+h]
#define OFF_PLOG  44048     // 256*16   [b*16 + c*8 + h]
#define OFF_SCT   48144     // 8193*8   pe[s*8+h] = e^{score}

static __device__ __forceinline__ float wred(float v) {
    #pragma unroll
    for (int m = 32; m; m >>= 1) v += __shfl_xor(v, m, 64);
    return v;
}

// DPP wave-64 sum, result broadcast to all lanes via readlane(63). VALU only.
#define DPPADD(v, ctrl) \
    ((v) + __int_as_float(__builtin_amdgcn_update_dpp( \
        0, __float_as_int(v), (ctrl), 0xf, 0xf, true)))

static __device__ __forceinline__ float wave_total(float v) {
    v = DPPADD(v, 0x111);   // row_shr:1
    v = DPPADD(v, 0x112);   // row_shr:2
    v = DPPADD(v, 0x114);   // row_shr:4
    v = DPPADD(v, 0x118);   // row_shr:8
    v = DPPADD(v, 0x142);   // row_bcast:15
    v = DPPADD(v, 0x143);   // row_bcast:31
    return __int_as_float(__builtin_amdgcn_readlane(__float_as_int(v), 63));
}

// ============ K1: qcls (blocks 0..255, 4 rows each) + E-partials (256..287) ==
__global__ __launch_bounds__(1024) void k1(const float* __restrict__ Wq,
                                           const float* __restrict__ bq,
                                           const float* __restrict__ ct,
                                           const float* __restrict__ Wc,
                                           const float* __restrict__ Wo,
                                           float* __restrict__ ws) {
    __shared__ float red[16];
    __shared__ float er[4][2][256];
    const int b = blockIdx.x, t = threadIdx.x;
    const int w = t >> 6, lane = t & 63;
    if (b < 256) {                        // qcls rows 4b..4b+3
        int grp = t >> 8, f4 = t & 255;
        int r = b * 4 + grp;
        const float4* wr = (const float4*)(Wq + (size_t)r * D);
        const float4* cv = (const float4*)ct;
        float4 a = wr[f4], c = cv[f4];
        float v = a.x*c.x + a.y*c.y + a.z*c.z + a.w*c.w;
        v = wred(v);
        if (lane == 0) red[w] = v;
        __syncthreads();
        if (t < 4)
            ws[OFF_QCLS + b*4 + t] = red[4*t]+red[4*t+1]+red[4*t+2]+red[4*t+3] + bq[b*4 + t];
    } else {                              // E-partial p over 128 Wo rows, j-quarter
        int idx = b - 256;                // 0..31
        int p = idx >> 2, jq = idx & 3;
        int layer = t >> 8, jl = t & 255;
        int j = jq * 256 + jl;
        int i0 = p * 128 + layer * 32;
        const float* wo = Wo + (size_t)i0 * D + j;
        float a0 = 0.f, a1 = 0.f;
        #pragma unroll 8
        for (int i = 0; i < 32; ++i) {
            float r = wo[(size_t)i * D];
            a0 += Wc[i0 + i] * r;
            a1 += Wc[D + i0 + i] * r;
        }
        er[layer][0][jl] = a0;
        er[layer][1][jl] = a1;
        __syncthreads();
        if (t < 512) {
            int c = t >> 8, jl2 = t & 255;
            ws[OFF_EP + p*2048 + c*1024 + jq*256 + jl2] =
                er[0][c][jl2] + er[1][c][jl2] + er[2][c][jl2] + er[3][c][jl2];
        }
    }
}

// ============ K2: w (0..63) + G (64..127) + ch (128) + const (129) ===========
__global__ __launch_bounds__(1024) void k2(const float* __restrict__ Wk,
                                           const float* __restrict__ bk,
                                           const float* __restrict__ Wv,
                                           const float* __restrict__ Wc,
                                           const float* __restrict__ bo,
                                           const float* __restrict__ bv,
                                           const float* __restrict__ bc,
                                           float* __restrict__ ws) {
    __shared__ float qh[128];
    __shared__ float el[2][128];
    __shared__ float lw[8][128];
    __shared__ float lg[8][2][128];
    __shared__ float red[32];
    const int b = blockIdx.x, t = threadIdx.x;
    const int w = t >> 6, lane = t & 63;
    if (b < 64) {                         // w[h, je*128..+128], 8 d-layers of 16
        int h = b >> 3, je = b & 7;
        if (t < 128) qh[t] = ws[OFF_QCLS + h*128 + t];
        __syncthreads();
        int layer = t >> 7, jl = t & 127;
        int j = je * 128 + jl, d0 = layer * 16;
        const float* wk = Wk + (size_t)(h*128 + d0) * D + j;
        float acc = 0.f;
        #pragma unroll 8
        for (int d = 0; d < 16; ++d) acc += qh[d0 + d] * wk[(size_t)d * D];
        lw[layer][jl] = acc;
        __syncthreads();
        if (t < 128) {
            float s = 0.f;
            #pragma unroll
            for (int i = 0; i < 8; ++i) s += lw[i][t];
            ws[OFF_W + h*1024 + je*128 + t] = s;
        }
    } else if (b < 128) {                 // G[c, h, je*128..+128], 8 r-layers of 16
        int hb = b - 64, h = hb >> 3, je = hb & 7;
        if (t < 256) {
            int c = t >> 7, r = t & 127;
            float s = 0.f;
            #pragma unroll
            for (int p = 0; p < 8; ++p) s += ws[OFF_EP + p*2048 + c*1024 + h*128 + r];
            el[c][r] = s;
        }
        __syncthreads();
        int layer = t >> 7, jl = t & 127;
        int j = je * 128 + jl, r0 = layer * 16;
        const float* wv = Wv + (size_t)(h*128 + r0) * D + j;
        float a0 = 0.f, a1 = 0.f;
        #pragma unroll 8
        for (int r = 0; r < 16; ++r) {
            float xv = wv[(size_t)r * D];
            a0 += el[0][r0 + r] * xv;
            a1 += el[1][r0 + r] * xv;
        }
        lg[layer][0][jl] = a0;
        lg[layer][1][jl] = a1;
        __syncthreads();
        if (t < 256) {
            int c = t >> 7, jl2 = t & 127;
            float s = 0.f;
            #pragma unroll
            for (int i = 0; i < 8; ++i) s += lg[i][c][jl2];
            ws[OFF_G + c*8192 + h*1024 + je*128 + jl2] = s;
        }
    } else if (b == 128) {                // ch[h] = qcls_h . bk_h
        int h = t >> 7, d = t & 127;
        float v = ws[OFF_QCLS + h*128 + d] * bk[h*128 + d];
        v = wred(v);
        if (lane == 0) red[w] = v;
        __syncthreads();
        if (t < 8) ws[OFF_CH + t] = red[2*t] + red[2*t+1];
    } else {                              // const_c = Wc.bo + E.bv + bc
        float e0 = 0.f, e1 = 0.f;
        #pragma unroll
        for (int p = 0; p < 8; ++p) {
            e0 += ws[OFF_EP + p*2048 + t];
            e1 += ws[OFF_EP + p*2048 + 1024 + t];
        }
        float v0 = Wc[t]*bo[t] + e0*bv[t];
        float v1 = Wc[D + t]*bo[t] + e1*bv[t];
        v0 = wred(v0); v1 = wred(v1);
        if (lane == 0) { red[w] = v0; red[16 + w] = v1; }
        __syncthreads();
        if (t == 0) {
            float a0 = 0.f, a1 = 0.f;
            #pragma unroll
            for (int i = 0; i < 16; ++i) { a0 += red[i]; a1 += red[16 + i]; }
            ws[OFF_CONST + 0] = a0 + bc[0];
            ws[OFF_CONST + 1] = a1 + bc[1];
        }
    }
}

// ============ K3: x single pass: pe + l_b + plog_b  (grid 256 x 512) =========
__global__ __launch_bounds__(512, 2) void k3(const float* __restrict__ x,
                                             const float* __restrict__ ct,
                                             float* __restrict__ ws) {
    __shared__ float stash[33 * D];       // 132 KB token rows
    __shared__ float pe[33][8];
    __shared__ float plred[8][8];
    const int b = blockIdx.x, t = threadIdx.x;
    const int w = t >> 6, lane = t & 63;

    // w fragments in VGPRs: lane l holds float4s {l, l+64, l+128, l+192}
    float4 wreg[8][4];
    const float4* wg4 = (const float4*)(ws + OFF_W);
    #pragma unroll
    for (int h = 0; h < 8; ++h)
        #pragma unroll
        for (int j = 0; j < 4; ++j)
            wreg[h][j] = wg4[h * 256 + j * 64 + lane];
    float chv[8];
    #pragma unroll
    for (int h = 0; h < 8; ++h) chv[h] = ws[OFF_CH + h];

    // async stash fill: wave w owns tokens w*4..w*4+3 (+k=32 for b=255,w=7)
    const int ntok_blk = (b == 255) ? 33 : 32;
    const bool tail = (b == 255 && w == 7);
    const int ntok_w = tail ? 5 : 4;
    for (int i = 0; i < ntok_w; ++i) {
        int k = (i < 4) ? (w * 4 + i) : 32;
        int s = b * 32 + k;
        const float* row = (s == 0) ? ct : (x + (size_t)(s - 1) * D);
        float* dst = stash + k * D;
        #pragma unroll
        for (int q = 0; q < 4; ++q)
            __builtin_amdgcn_global_load_lds(
                (const __attribute__((address_space(1))) unsigned int*)(row + q * 256 + lane * 4),
                (__attribute__((address_space(3))) unsigned int*)(dst + q * 256),
                16, 0, 0);
    }

    const float scale = 0.08838834764831845f;   // 1/sqrt(128)
    auto compute = [&](int k) {
        int s = b * 32 + k;
        const float4* tk = (const float4*)(stash + k * D);
        float4 t0 = tk[lane], t1 = tk[64 + lane], t2 = tk[128 + lane], t3 = tk[192 + lane];
        float pv[8];
        #pragma unroll
        for (int h = 0; h < 8; ++h) {
            float4 w0 = wreg[h][0], w1 = wreg[h][1], w2 = wreg[h][2], w3 = wreg[h][3];
            float v = w0.x*t0.x + w0.y*t0.y + w0.z*t0.z + w0.w*t0.w
                    + w1.x*t1.x + w1.y*t1.y + w1.z*t1.z + w1.w*t1.w
                    + w2.x*t2.x + w2.y*t2.y + w2.z*t2.z + w2.w*t2.w
                    + w3.x*t3.x + w3.y*t3.y + w3.z*t3.z + w3.w*t3.w;
            v = wave_total(v);
            pv[h] = __expf(scale * (v + chv[h]));
        }
        if (lane == 0) {
            float4* sct = (float4*)(ws + OFF_SCT);
            sct[s * 2]     = make_float4(pv[0], pv[1], pv[2], pv[3]);
            sct[s * 2 + 1] = make_float4(pv[4], pv[5], pv[6], pv[7]);
            *(float4*)&pe[k][0] = make_float4(pv[0], pv[1], pv[2], pv[3]);
            *(float4*)&pe[k][4] = make_float4(pv[4], pv[5], pv[6], pv[7]);
        }
    };

    if (!tail) {                          // overlap fetch & compute per token
        __builtin_amdgcn_s_waitcnt(0x0f7c); compute(w*4 + 0);   // vmcnt(12)
        __builtin_amdgcn_s_waitcnt(0x0f78); compute(w*4 + 1);   // vmcnt(8)
        __builtin_amdgcn_s_waitcnt(0x0f74); compute(w*4 + 2);   // vmcnt(4)
        __builtin_amdgcn_s_waitcnt(0x0f70); compute(w*4 + 3);   // vmcnt(0)
    } else {
        __builtin_amdgcn_s_waitcnt(0x0f70);
        for (int i = 0; i < 5; ++i) compute((i < 4) ? (w*4 + i) : 32);
    }
    __syncthreads();

    // l_b[h]
    if (t < 8) {
        float s = 0.f;
        for (int k = 0; k < ntok_blk; ++k) s += pe[k][t];
        ws[OFF_L + b * 8 + t] = s;
    }

    // u_b in registers: thread (half, f4) owns heads 4*half.., float4 j-slice f4
    const int f4 = t & 255, half = t >> 8;
    const float4* st4 = (const float4*)stash;
    float4 acc0 = {0,0,0,0}, acc1 = {0,0,0,0}, acc2 = {0,0,0,0}, acc3 = {0,0,0,0};
    for (int k = 0; k < ntok_blk; ++k) {
        float4 tv = st4[k * 256 + f4];
        float4 pv = *(const float4*)&pe[k][half * 4];
        acc0.x += pv.x*tv.x; acc0.y += pv.x*tv.y; acc0.z += pv.x*tv.z; acc0.w += pv.x*tv.w;
        acc1.x += pv.y*tv.x; acc1.y += pv.y*tv.y; acc1.z += pv.y*tv.z; acc1.w += pv.y*tv.w;
        acc2.x += pv.z*tv.x; acc2.y += pv.z*tv.y; acc2.z += pv.z*tv.z; acc2.w += pv.z*tv.w;
        acc3.x += pv.w*tv.x; acc3.y += pv.w*tv.y; acc3.z += pv.w*tv.z; acc3.w += pv.w*tv.w;
    }

    // plog_b[c][h] = G[c,h,:] . u_b[h,:]   (G is L2-hot, 64 KB total)
    const float4* G4 = (const float4*)(ws + OFF_G);
    float pl[8];
    #pragma unroll
    for (int c = 0; c < 2; ++c) {
        float4 g0 = G4[c*2048 + (half*4 + 0)*256 + f4];
        float4 g1 = G4[c*2048 + (half*4 + 1)*256 + f4];
        float4 g2 = G4[c*2048 + (half*4 + 2)*256 + f4];
        float4 g3 = G4[c*2048 + (half*4 + 3)*256 + f4];
        pl[c*4+0] = g0.x*acc0.x + g0.y*acc0.y + g0.z*acc0.z + g0.w*acc0.w;
        pl[c*4+1] = g1.x*acc1.x + g1.y*acc1.y + g1.z*acc1.z + g1.w*acc1.w;
        pl[c*4+2] = g2.x*acc2.x + g2.y*acc2.y + g2.z*acc2.z + g2.w*acc2.w;
        pl[c*4+3] = g3.x*acc3.x + g3.y*acc3.y + g3.z*acc3.z + g3.w*acc3.w;
    }
    #pragma unroll
    for (int v = 0; v < 8; ++v) pl[v] = wave_total(pl[v]);
    if (lane == 0)
        #pragma unroll
        for (int v = 0; v < 8; ++v) plred[w][v] = pl[v];
    __syncthreads();
    if (t < 16) {                         // combine 4 waves per half
        int c = t >> 3, hh = t & 7;
        int wb = (hh < 4) ? 0 : 4, vi = c * 4 + (hh & 3);
        ws[OFF_PLOG + b*16 + t] =
            plred[wb][vi] + plred[wb+1][vi] + plred[wb+2][vi] + plred[wb+3][vi];
    }
}

// ============ K4: rlh + A + logits (block 0)  (grid 256 x 256) ===============
__global__ __launch_bounds__(256) void k4(float* __restrict__ out,
                                          float* __restrict__ ws) {
    __shared__ float lp[32][8];
    __shared__ float rlh[8];
    __shared__ float r2[8];
    const int b = blockIdx.x, t = threadIdx.x;

    {   // global 1/l_h (redundant per block)
        int seg = t >> 3, h = t & 7;
        float s = 0.f;
        for (int pb = seg; pb < 256; pb += 32) s += ws[OFF_L + pb*8 + h];
        lp[seg][h] = s;
    }
    __syncthreads();
    if (t < 8) {
        float s = 0.f;
        #pragma unroll
        for (int i = 0; i < 32; ++i) s += lp[i][t];
        rlh[t] = 1.f / s;
    }
    __syncthreads();

    // A[s], s = b*32 + t + 1  (pe already stored in SCT)
    if (t < 32) {
        int s_ = b * 32 + t + 1;
        const float4* sct = (const float4*)(ws + OFF_SCT);
        float4 pa = sct[s_ * 2], pb4 = sct[s_ * 2 + 1];
        float sum = pa.x*rlh[0] + pa.y*rlh[1] + pa.z*rlh[2] + pa.w*rlh[3]
                  + pb4.x*rlh[4] + pb4.y*rlh[5] + pb4.z*rlh[6] + pb4.w*rlh[7];
        out[6 + s_] = sum * 0.125f;
    }

    if (b == 0) {                         // logits + scalar outputs
        float v0 = 0.f, v1 = 0.f;
        for (int idx = t; idx < 4096; idx += 256) {
            float val = ws[OFF_PLOG + idx];
            int rem = idx & 15;
            float z = val * rlh[rem & 7];
            if ((rem >> 3) == 0) v0 += z; else v1 += z;
        }
        v0 = wred(v0); v1 = wred(v1);
        if ((t & 63) == 0) { r2[t >> 6] = v0; r2[4 + (t >> 6)] = v1; }
        __syncthreads();
        if (t == 0) {
            float l0 = r2[0]+r2[1]+r2[2]+r2[3] + ws[OFF_CONST + 0];
            float l1 = r2[4]+r2[5]+r2[6]+r2[7] + ws[OFF_CONST + 1];
            float mx = fmaxf(l0, l1);
            float e0 = __expf(l0 - mx), e1 = __expf(l1 - mx);
            float inv = 1.f / (e0 + e1);
            float p0 = e0 * inv, p1 = e1 * inv;
            int am = (p1 > p0) ? 1 : 0;
            out[0] = l0; out[1] = l1;
            out[2] = p0; out[3] = p1;
            out[4] = (float)am;
            out[5] = p0; out[6] = p1;
        }
    }
}

extern "C" void kernel_launch(void* const* d_in, const int* in_sizes, int n_in,
                              void* d_out, int out_size, void* d_ws, size_t ws_size,
                              hipStream_t stream) {
    const float* x  = (const float*)d_in[0];
    const float* ct = (const float*)d_in[1];
    const float* Wq = (const float*)d_in[2];
    const float* bq = (const float*)d_in[3];
    const float* Wk = (const float*)d_in[4];
    const float* bk = (const float*)d_in[5];
    const float* Wv = (const float*)d_in[6];
    const float* bv = (const float*)d_in[7];
    const float* Wo = (const float*)d_in[8];
    const float* bo = (const float*)d_in[9];
    const float* Wc = (const float*)d_in[10];
    const float* bc = (const float*)d_in[11];
    float* out = (float*)d_out;
    float* ws  = (float*)d_ws;

    k1<<<dim3(288), dim3(1024), 0, stream>>>(Wq, bq, ct, Wc, Wo, ws);
    k2<<<dim3(130), dim3(1024), 0, stream>>>(Wk, bk, Wv, Wc, bo, bv, bc, ws);
    k3<<<dim3(256), dim3(512),  0, stream>>>(x, ct, ws);
    k4<<<dim3(256), dim3(256),  0, stream>>>(out, ws);
}